// Round 4
// baseline (507.357 us; speedup 1.0000x reference)
//
#include <hip/hip_runtime.h>
#include <math.h>

// S4D block, MI355X round 4: scan with LDS-broadcast power tables (VGPR diet).
// B=8, H=256, T=8192, N=16 complex states.

#define TN 8192
#define HN 256
#define BN 8
#define NS 16

typedef __bf16 bf16x8 __attribute__((ext_vector_type(8)));
typedef __bf16 bf16x4 __attribute__((ext_vector_type(4)));
typedef __bf16 bf16x2 __attribute__((ext_vector_type(2)));
typedef float  f32x4  __attribute__((ext_vector_type(4)));

__device__ __forceinline__ float gelu_f(float v) {
    return 0.5f * v * (1.f + erff(v * 0.70710678118654752440f));
}
__device__ __forceinline__ float sigm_f(float v) {
    return 1.f / (1.f + expf(-v));
}

// ---------------- SSM constant prep: store dt*A (for power table) + 2*Cmod ----------------
__global__ void prep_kernel(const float* __restrict__ log_dt,
                            const float* __restrict__ C_re,
                            const float* __restrict__ C_im,
                            const float* __restrict__ log_A_real,
                            const float* __restrict__ A_imag,
                            float* __restrict__ P)
{
    int i = blockIdx.x * 64 + threadIdx.x;   // 0..4095
    int h = i >> 4;
    float dt = expf(log_dt[h]);
    float Ar = -expf(log_A_real[i]);
    float Ai = A_imag[i];
    float dar = Ar * dt, dai = Ai * dt;
    float er = expf(dar);
    float ar = er * cosf(dai);
    float ai = er * sinf(dai);
    float Er = ar - 1.f, Ei = ai;
    float inv = 1.f / (Ar * Ar + Ai * Ai);
    float Fr = (Er * Ar + Ei * Ai) * inv;
    float Fi = (Ei * Ar - Er * Ai) * inv;
    float cr = C_re[i] * Fr - C_im[i] * Fi;
    float ci = C_re[i] * Fi + C_im[i] * Fr;
    P[i]           = dar;
    P[4096 + i]    = dai;
    P[2*4096 + i]  = 2.f * cr;
    P[3*4096 + i]  = 2.f * ci;
}

// ---------------- weight prep: fp32 -> bf16, tiled+swizzled LDS image ----------------
__global__ void prep_w_kernel(const float* __restrict__ W, __bf16* __restrict__ Wp,
                              int K, int glu)
{
    int id = blockIdx.x * 256 + threadIdx.x;
    int nK = K >> 6;
    int c = id >> 10, r = (id >> 3) & 127, s = id & 7;
    int mt = c / nK, kt = c - mt * nK;
    int R = mt * 128 + r;
    int row = glu ? ((R & 1) ? (R >> 1) + 256 : (R >> 1)) : R;
    int k = kt * 64 + ((s ^ (r & 7)) << 3);
    const float* src = W + (size_t)row * K + k;
    __bf16 o[8];
    #pragma unroll
    for (int j = 0; j < 8; ++j) o[j] = (__bf16)src[j];
    *(uint4*)(Wp + (size_t)id * 8) = *(uint4*)o;
}

// ---------------- channel-LN stats for [B][H][T] fp32 ----------------
__global__ __launch_bounds__(256) void ln_stats_kernel(const float* __restrict__ X,
                                                       float* __restrict__ mu,
                                                       float* __restrict__ rs)
{
    int b = blockIdx.y;
    int t = blockIdx.x * 256 + threadIdx.x;
    const float* p = X + (size_t)b * HN * TN + t;
    float s = 0.f, ss = 0.f;
    #pragma unroll 8
    for (int c = 0; c < HN; ++c) {
        float v = p[(size_t)c * TN];
        s += v; ss += v * v;
    }
    float m = s * (1.f / HN);
    float var = ss * (1.f / HN) - m * m;
    mu[b * TN + t] = m;
    rs[b * TN + t] = rsqrtf(var + 1e-5f);
}

// ---------------- channel-LN stats for [B][T][H] fp32 (channels-last) ----------------
__global__ __launch_bounds__(256) void ln_stats_cl_kernel(const float* __restrict__ A,
                                                          float* __restrict__ mu,
                                                          float* __restrict__ rs)
{
    int row = blockIdx.x * 4 + (threadIdx.x >> 6);   // b*T + t
    int l = threadIdx.x & 63;
    float4 v = *(const float4*)(A + ((size_t)row << 8) + l * 4);
    float s  = v.x + v.y + v.z + v.w;
    float ss = v.x*v.x + v.y*v.y + v.z*v.z + v.w*v.w;
    #pragma unroll
    for (int d = 32; d; d >>= 1) { s += __shfl_down(s, d, 64); ss += __shfl_down(ss, d, 64); }
    if (l == 0) {
        float m = s * (1.f / 256.f);
        mu[row] = m;
        rs[row] = rsqrtf(ss * (1.f / 256.f) - m * m + 1e-5f);
    }
}

// ---------------- transpose [B][H][T] (f32 or bf16) -> [B][T][H] bf16 ----------------
template<typename TI>
__global__ __launch_bounds__(256) void transpose_kernel(const TI* __restrict__ in,
                                                        __bf16* __restrict__ out)
{
    __shared__ float tile[64][65];
    int b = blockIdx.z, h0 = blockIdx.y * 64, t0 = blockIdx.x * 64;
    int tid = threadIdx.x;
    int hl = tid >> 2, pr = tid & 3;
    const TI* src = in + ((size_t)(b * HN + h0 + hl)) * TN + t0 + pr * 16;
    if constexpr (sizeof(TI) == 4) {
        #pragma unroll
        for (int j = 0; j < 4; ++j) {
            float4 v = *(const float4*)((const float*)src + j * 4);
            *(float4*)&tile[hl][pr * 16 + j * 4] = v;
        }
    } else {
        #pragma unroll
        for (int p = 0; p < 2; ++p) {
            bf16x8 v = *(const bf16x8*)((const __bf16*)src + p * 8);
            #pragma unroll
            for (int j = 0; j < 8; ++j) tile[hl][pr * 16 + p * 8 + j] = (float)v[j];
        }
    }
    __syncthreads();
    int tl = tid >> 2;
    __bf16 o[16];
    #pragma unroll
    for (int j = 0; j < 16; ++j) o[j] = (__bf16)tile[pr * 16 + j][tl];
    __bf16* dst = out + ((size_t)(b * TN + t0 + tl)) * HN + h0 + pr * 16;
    *(uint4*)dst = *(uint4*)&o[0];
    *(uint4*)(dst + 8) = *(uint4*)&o[8];
}

// ---------------- S4D scan, block-per-row, LDS power tables ----------------
// 256 threads = 256 chunks of 32; pitch-33 LDS row image.
// Tables (shared per block, broadcast reads):
//   pow[j][n] = a^j, j=0..32;  ksd[k][n] = a^(32*2^k), k=0..6;  c2l = 2*Cmod.
__global__ __launch_bounds__(256) void scan_kernel(const float* __restrict__ X,
                                                   const float* __restrict__ mu,
                                                   const float* __restrict__ rs,
                                                   const float* __restrict__ g1,
                                                   const float* __restrict__ b1,
                                                   const float* __restrict__ Dp,
                                                   const float* __restrict__ P,
                                                   __bf16* __restrict__ GU)
{
    __shared__ float ylds[8448];          // 256 chunks x pitch 33
    __shared__ float powr[528], powi[528];
    __shared__ float ksdr[7][16], ksdi[7][16];
    __shared__ float c2lr[16], c2li[16];
    __shared__ float wtot[4][NS][2];
    int row = blockIdx.x;
    int b = row >> 8, h = row & 255;
    int tid = threadIdx.x;
    int w = tid >> 6, lane = tid & 63;

    float gh = g1[h], bh = b1[h], dh = Dp[h];
    const float* xrow = X + (size_t)(b * HN + h) * TN;
    const float* mup = mu + b * TN;
    const float* rsp = rs + b * TN;

    // ---- stage row + inline LN1 (coalesced float4) ----
    #pragma unroll
    for (int s = 0; s < 8; ++s) {
        int t = (s * 256 + tid) * 4;
        float4 xv = *(const float4*)(xrow + t);
        float4 m4 = *(const float4*)(mup + t);
        float4 r4 = *(const float4*)(rsp + t);
        float* dst = &ylds[(t >> 5) * 33 + (t & 31)];
        dst[0] = fmaf((xv.x - m4.x) * r4.x, gh, bh);
        dst[1] = fmaf((xv.y - m4.y) * r4.y, gh, bh);
        dst[2] = fmaf((xv.z - m4.z) * r4.z, gh, bh);
        dst[3] = fmaf((xv.w - m4.w) * r4.w, gh, bh);
    }

    // ---- build pow table: a^j = exp(j*dtAr) * cis(j*dtAi) ----
    for (int idx = tid; idx < 528; idx += 256) {
        int j = idx >> 4, n = idx & 15;
        float dar = P[h * NS + n], dai = P[4096 + h * NS + n];
        float er = expf((float)j * dar);
        float ph = (float)j * dai;
        powr[idx] = er * cosf(ph);
        powi[idx] = er * sinf(ph);
    }
    __syncthreads();

    // ---- build ksd (a^(32*2^k)) + stage c2 ----
    if (tid < 16) {
        int n = tid;
        float kr = powr[512 + n], ki = powi[512 + n];   // a^32
        ksdr[0][n] = kr; ksdi[0][n] = ki;
        #pragma unroll
        for (int k = 1; k < 7; ++k) {
            float t2 = kr * kr - ki * ki; ki = 2.f * kr * ki; kr = t2;
            ksdr[k][n] = kr; ksdi[k][n] = ki;
        }
        c2lr[n] = P[2*4096 + h * NS + n];
        c2li[n] = P[3*4096 + h * NS + n];
    }
    __syncthreads();

    float ar[NS], ai[NS];
    #pragma unroll
    for (int n = 0; n < NS; ++n) { ar[n] = powr[16 + n]; ai[n] = powi[16 + n]; }

    // ---- phase 1: local chunk scan ----
    float sr[NS], si[NS];
    #pragma unroll
    for (int n = 0; n < NS; ++n) { sr[n] = 0.f; si[n] = 0.f; }
    const float* yc = &ylds[tid * 33];
    for (int j = 0; j < 32; ++j) {
        float y = yc[j];
        #pragma unroll
        for (int n = 0; n < NS; ++n) {
            float nr = fmaf(ar[n], sr[n], fmaf(-ai[n], si[n], y));
            float ni = fmaf(ar[n], si[n], ai[n] * sr[n]);
            sr[n] = nr; si[n] = ni;
        }
    }

    // ---- wave Kogge-Stone, decays from LDS table ----
    #pragma unroll
    for (int k = 0; k < 6; ++k) {
        int d = 1 << k;
        #pragma unroll
        for (int n = 0; n < NS; ++n) {
            float qpr = __shfl_up(sr[n], (unsigned)d, 64);
            float qpi = __shfl_up(si[n], (unsigned)d, 64);
            if (lane >= d) {
                float pdr = ksdr[k][n], pdi = ksdi[k][n];
                float nqr = fmaf(pdr, qpr, fmaf(-pdi, qpi, sr[n]));
                float nqi = fmaf(pdr, qpi, fmaf(pdi, qpr, si[n]));
                sr[n] = nqr; si[n] = nqi;
            }
        }
    }
    if (lane == 63) {
        #pragma unroll
        for (int n = 0; n < NS; ++n) { wtot[w][n][0] = sr[n]; wtot[w][n][1] = si[n]; }
    }
    __syncthreads();

    // ---- per-lane init: a^(32*lane) * S_w + incl(lane-1), powers from ksd ----
    #pragma unroll
    for (int n = 0; n < NS; ++n) {
        float Lr = __shfl_up(sr[n], 1u, 64);
        float Li = __shfl_up(si[n], 1u, 64);
        if (lane == 0) { Lr = 0.f; Li = 0.f; }
        float Sr = 0.f, Si = 0.f;
        float d6r = ksdr[6][n], d6i = ksdi[6][n];
        for (int v = 0; v < w; ++v) {
            float tr = d6r * Sr - d6i * Si + wtot[v][n][0];
            float ti = d6r * Si + d6i * Sr + wtot[v][n][1];
            Sr = tr; Si = ti;
        }
        float qr = 1.f, qi = 0.f;
        #pragma unroll
        for (int k = 0; k < 6; ++k) {
            if ((lane >> k) & 1) {
                float kr = ksdr[k][n], ki = ksdi[k][n];
                float t2 = qr * kr - qi * ki; qi = qr * ki + qi * kr; qr = t2;
            }
        }
        sr[n] = qr * Sr - qi * Si + Lr;
        si[n] = qr * Si + qi * Sr + Li;
    }

    // ---- phase 2: rescan with init, gelu(u) back into LDS ----
    float c2r[NS], c2i[NS];
    #pragma unroll
    for (int n = 0; n < NS; ++n) { c2r[n] = c2lr[n]; c2i[n] = c2li[n]; }
    float* yw = &ylds[tid * 33];
    for (int j = 0; j < 32; ++j) {
        float y = yw[j];
        float u = dh * y;
        #pragma unroll
        for (int n = 0; n < NS; ++n) {
            float nr = fmaf(ar[n], sr[n], fmaf(-ai[n], si[n], y));
            float ni = fmaf(ar[n], si[n], ai[n] * sr[n]);
            sr[n] = nr; si[n] = ni;
            u = fmaf(c2r[n], nr, fmaf(-c2i[n], ni, u));
        }
        yw[j] = gelu_f(u);
    }
    __syncthreads();

    // ---- coalesced bf16 write ----
    __bf16* gout = GU + (size_t)(b * HN + h) * TN;
    #pragma unroll
    for (int s = 0; s < 8; ++s) {
        int t = (s * 256 + tid) * 4;
        const float* src = &ylds[(t >> 5) * 33 + (t & 31)];
        bf16x4 ov;
        ov[0] = (__bf16)src[0]; ov[1] = (__bf16)src[1];
        ov[2] = (__bf16)src[2]; ov[3] = (__bf16)src[3];
        *(bf16x4*)(gout + t) = ov;
    }
}

// ---------------- MFMA conv1x1 GEMM, channels-last ----------------
// OMODE 0: bf16 out [B][T][H];  1: fp32 A_cl [B][T][H] = GLU + bf16 resB (cl), LDS-transposed;
// OMODE 2: fp32 out [B][H][T] += resF (fp32 cl), LDS-transposed store.
template<int K, bool GLU, bool CONCAT, bool LNIN, bool GELUOUT, int OMODE>
__global__ __launch_bounds__(256) void gemm_cl_kernel(
    const __bf16* __restrict__ B0, const __bf16* __restrict__ B1,
    const float*  __restrict__ BF,
    const __bf16* __restrict__ Wp, const float* __restrict__ bias,
    const float* __restrict__ mu, const float* __restrict__ rsd,
    const float* __restrict__ lng, const float* __restrict__ lnb,
    const float* __restrict__ resF, const __bf16* __restrict__ resB,
    float* __restrict__ outF, __bf16* __restrict__ outB)
{
    constexpr int nK = K / 64;
    constexpr int LDSSZ = (OMODE != 0) ? 34816 : 32768;
    __shared__ __align__(16) char lds[LDSSZ];
    char* sA = lds;
    char* sB = lds + 16384;
    int tid = threadIdx.x;
    int w = tid >> 6, wr = w >> 1, wc = w & 1;
    int b = blockIdx.z, by = blockIdx.y;
    int t0 = blockIdx.x * 128;
    int lane = tid & 63;
    int lr = tid & 15, lg = (tid >> 4) & 3;
    int rl = lane >> 3, sl = lane & 7;

    f32x4 acc[4][4];
    #pragma unroll
    for (int i = 0; i < 4; ++i)
        #pragma unroll
        for (int j = 0; j < 4; ++j) acc[i][j] = (f32x4){0.f, 0.f, 0.f, 0.f};

    for (int kt = 0; kt < nK; ++kt) {
        {
            const char* asrc = (const char*)Wp + (((size_t)by * nK + kt) << 14)
                               + w * 4096 + lane * 16;
            char* adst = sA + w * 4096;
            #pragma unroll
            for (int i = 0; i < 4; ++i)
                __builtin_amdgcn_global_load_lds(
                    (const __attribute__((address_space(1))) void*)(asrc + i * 1024),
                    (__attribute__((address_space(3))) void*)(adst + i * 1024), 16, 0, 0);
        }
        if constexpr (!LNIN) {
            int kg = kt * 64;
            const __bf16* base = (CONCAT && kg >= 256) ? B1 : B0;
            int kloc = (CONCAT && kg >= 256) ? kg - 256 : kg;
            #pragma unroll
            for (int i = 0; i < 4; ++i) {
                int rb = w * 32 + i * 8 + rl;
                const char* gs = (const char*)(base + (((size_t)(b * TN + t0 + rb)) << 8) + kloc)
                                 + ((sl ^ rl) << 4);
                __builtin_amdgcn_global_load_lds(
                    (const __attribute__((address_space(1))) void*)gs,
                    (__attribute__((address_space(3))) void*)(sB + w * 4096 + i * 1024), 16, 0, 0);
            }
        } else {
            #pragma unroll
            for (int i = 0; i < 8; ++i) {
                int q = i * 256 + tid;
                int r = q >> 4, qs = q & 15;
                int t = t0 + r;
                const float* src = BF + (((size_t)(b * TN + t)) << 8) + kt * 64 + qs * 4;
                float4 v = *(const float4*)src;
                float m_ = mu[b * TN + t], rr = rsd[b * TN + t];
                float4 g4 = *(const float4*)(lng + kt * 64 + qs * 4);
                float4 b4 = *(const float4*)(lnb + kt * 64 + qs * 4);
                __bf16 o[4];
                o[0] = (__bf16)fmaf((v.x - m_) * rr, g4.x, b4.x);
                o[1] = (__bf16)fmaf((v.y - m_) * rr, g4.y, b4.y);
                o[2] = (__bf16)fmaf((v.z - m_) * rr, g4.z, b4.z);
                o[3] = (__bf16)fmaf((v.w - m_) * rr, g4.w, b4.w);
                int off = r * 128 + ((((qs >> 1) ^ (r & 7))) << 4) + (qs & 1) * 8;
                *(uint2*)(sB + off) = *(uint2*)o;
            }
        }
        __syncthreads();

        const char* aB = sA + (wr * 64 + lr) * 128;
        const char* bB = sB + (wc * 64 + lr) * 128;
        int swz = (lr & 7) << 4;
        #pragma unroll
        for (int ks = 0; ks < 2; ++ks) {
            int ko = (ks * 64 + lg * 16) ^ swz;
            bf16x8 af[4], bfr[4];
            #pragma unroll
            for (int f = 0; f < 4; ++f) af[f]  = *(const bf16x8*)(aB + f * 2048 + ko);
            #pragma unroll
            for (int f = 0; f < 4; ++f) bfr[f] = *(const bf16x8*)(bB + f * 2048 + ko);
            #pragma unroll
            for (int fm = 0; fm < 4; ++fm)
                #pragma unroll
                for (int fn = 0; fn < 4; ++fn)
                    acc[fm][fn] = __builtin_amdgcn_mfma_f32_16x16x32_bf16(
                        af[fm], bfr[fn], acc[fm][fn], 0, 0, 0);
        }
        __syncthreads();
    }

    int tcb = t0 + wc * 64 + lr;
    int mrow0 = by * 128 + wr * 64 + lg * 4;

    if constexpr (OMODE == 1) {
        float* tile = (float*)lds;
        #pragma unroll
        for (int fm = 0; fm < 4; ++fm) {
            int R0 = mrow0 + fm * 16;
            int c_ = R0 >> 1;
            int cloc = c_ - by * 64;
            #pragma unroll
            for (int fn = 0; fn < 4; ++fn) {
                f32x4 v = acc[fm][fn];
                float a0 = v[0] + bias[c_],     g0 = v[1] + bias[c_ + 256];
                float a1 = v[2] + bias[c_ + 1], g1 = v[3] + bias[c_ + 257];
                float o0 = a0 * sigm_f(g0), o1 = a1 * sigm_f(g1);
                if constexpr (GELUOUT) { o0 = gelu_f(o0); o1 = gelu_f(o1); }
                int tl = wc * 64 + lr + fn * 16;
                *(float2*)&tile[tl * 68 + cloc] = make_float2(o0, o1);
            }
        }
        __syncthreads();
        #pragma unroll
        for (int it = 0; it < 8; ++it) {
            int fid = it * 256 + tid;
            int tl = fid >> 4, f = (fid & 15) << 2;
            size_t go = (((size_t)(b * TN + t0 + tl)) << 8) + by * 64 + f;
            float4 v = *(const float4*)&tile[tl * 68 + f];
            bf16x4 xr = *(const bf16x4*)(resB + go);
            v.x += (float)xr[0]; v.y += (float)xr[1];
            v.z += (float)xr[2]; v.w += (float)xr[3];
            *(float4*)(outF + go) = v;
        }
    } else if constexpr (OMODE == 2) {
        float* tile = (float*)lds;
        #pragma unroll
        for (int ht = 0; ht < 2; ++ht) {
            if (wc == ht) {
                #pragma unroll
                for (int fm = 0; fm < 4; ++fm) {
                    int R0 = mrow0 + fm * 16;
                    int mloc = R0 - by * 128;
                    #pragma unroll
                    for (int fn = 0; fn < 4; ++fn) {
                        int t = tcb + fn * 16;
                        f32x4 v = acc[fm][fn];
                        float4 rv = *(const float4*)(resF + (((size_t)(b * TN + t)) << 8) + R0);
                        int tloc = lr + fn * 16;
                        tile[(mloc + 0) * 68 + tloc] = v[0] + bias[R0 + 0] + rv.x;
                        tile[(mloc + 1) * 68 + tloc] = v[1] + bias[R0 + 1] + rv.y;
                        tile[(mloc + 2) * 68 + tloc] = v[2] + bias[R0 + 2] + rv.z;
                        tile[(mloc + 3) * 68 + tloc] = v[3] + bias[R0 + 3] + rv.w;
                    }
                }
            }
            __syncthreads();
            #pragma unroll
            for (int it = 0; it < 8; ++it) {
                int fid = it * 256 + tid;
                int m = fid >> 4, f = (fid & 15) << 2;
                float4 v = *(const float4*)&tile[m * 68 + f];
                *(float4*)(outF + ((size_t)(b * HN + by * 128 + m)) * TN + t0 + ht * 64 + f) = v;
            }
            __syncthreads();
        }
    } else {
        #pragma unroll
        for (int fm = 0; fm < 4; ++fm) {
            int R0 = mrow0 + fm * 16;
            #pragma unroll
            for (int fn = 0; fn < 4; ++fn) {
                int t = tcb + fn * 16;
                f32x4 v = acc[fm][fn];
                size_t rowoff = ((size_t)(b * TN + t)) << 8;
                if constexpr (GLU) {
                    int c_ = R0 >> 1;
                    float a0 = v[0] + bias[c_],     g0 = v[1] + bias[c_ + 256];
                    float a1 = v[2] + bias[c_ + 1], g1 = v[3] + bias[c_ + 257];
                    float o0 = a0 * sigm_f(g0), o1 = a1 * sigm_f(g1);
                    if constexpr (GELUOUT) { o0 = gelu_f(o0); o1 = gelu_f(o1); }
                    bf16x2 ov; ov[0] = (__bf16)o0; ov[1] = (__bf16)o1;
                    *(bf16x2*)(outB + rowoff + c_) = ov;
                } else {
                    float vv[4];
                    #pragma unroll
                    for (int j = 0; j < 4; ++j) vv[j] = v[j] + bias[R0 + j];
                    if constexpr (GELUOUT) {
                        #pragma unroll
                        for (int j = 0; j < 4; ++j) vv[j] = gelu_f(vv[j]);
                    }
                    bf16x4 ov;
                    #pragma unroll
                    for (int j = 0; j < 4; ++j) ov[j] = (__bf16)vv[j];
                    *(bf16x4*)(outB + rowoff + R0) = ov;
                }
            }
        }
    }
}

extern "C" void kernel_launch(void* const* d_in, const int* in_sizes, int n_in,
                              void* d_out, int out_size, void* d_ws, size_t ws_size,
                              hipStream_t stream)
{
    (void)in_sizes; (void)n_in; (void)out_size; (void)ws_size;
    const float* x      = (const float*)d_in[0];
    const float* log_dt = (const float*)d_in[1];
    const float* C_re   = (const float*)d_in[2];
    const float* C_im   = (const float*)d_in[3];
    const float* logAr  = (const float*)d_in[4];
    const float* A_im   = (const float*)d_in[5];
    const float* Dp     = (const float*)d_in[6];
    const float* outW   = (const float*)d_in[7];
    const float* outB   = (const float*)d_in[8];
    const float* ln1g   = (const float*)d_in[9];
    const float* ln1b   = (const float*)d_in[10];
    const float* lin1W  = (const float*)d_in[11];
    const float* lin1b  = (const float*)d_in[12];
    const float* gluW   = (const float*)d_in[13];
    const float* glub   = (const float*)d_in[14];
    const float* ln2g   = (const float*)d_in[15];
    const float* ln2b   = (const float*)d_in[16];
    const float* ff2aW  = (const float*)d_in[17];
    const float* ff2ab  = (const float*)d_in[18];
    const float* ff2bW  = (const float*)d_in[19];
    const float* ff2bb  = (const float*)d_in[20];
    float* out = (float*)d_out;

    char* ws = (char*)d_ws;
    const size_t MB = 1u << 20;
    float*  P    = (float*)(ws);
    float*  mu1  = (float*)(ws + 0x40000);
    float*  rs1  = (float*)(ws + 0x80000);
    float*  mu2  = (float*)(ws + 0xC0000);
    float*  rs2  = (float*)(ws + 0x100000);
    __bf16* WpO  = (__bf16*)(ws + 0x140000);
    __bf16* WpL  = (__bf16*)(ws + 0x180000);
    __bf16* WpG  = (__bf16*)(ws + 0x1A0000);
    __bf16* WpA  = (__bf16*)(ws + 0x220000);
    __bf16* WpB  = (__bf16*)(ws + 0x240000);
    __bf16* x_cl = (__bf16*)(ws + 4 * MB);     // 32MB [B][T][H] bf16
    char*   slB  = ws + 36 * MB;               // 32MB
    char*   slC  = ws + 68 * MB;               // 32MB
    float*  A_cl = (float*)(ws + 68 * MB);     // 64MB fp32

    prep_kernel<<<64, 64, 0, stream>>>(log_dt, C_re, C_im, logAr, A_im, P);
    prep_w_kernel<<<64, 256, 0, stream>>>(outW,  WpO, 256, 1);
    prep_w_kernel<<<32, 256, 0, stream>>>(lin1W, WpL, 256, 0);
    prep_w_kernel<<<128, 256, 0, stream>>>(gluW, WpG, 512, 1);
    prep_w_kernel<<<32, 256, 0, stream>>>(ff2aW, WpA, 256, 0);
    prep_w_kernel<<<32, 256, 0, stream>>>(ff2bW, WpB, 256, 0);

    ln_stats_kernel<<<dim3(32, BN), 256, 0, stream>>>(x, mu1, rs1);
    transpose_kernel<float><<<dim3(128, 4, BN), 256, 0, stream>>>(x, x_cl);

    __bf16* gu_raw = (__bf16*)slC;
    __bf16* gu_cl  = (__bf16*)slB;
    scan_kernel<<<2048, 256, 0, stream>>>(x, mu1, rs1, ln1g, ln1b, Dp, P, gu_raw);
    transpose_kernel<__bf16><<<dim3(128, 4, BN), 256, 0, stream>>>(gu_raw, gu_cl);

    dim3 g2(64, 2, BN), g4(64, 4, BN);
    __bf16* y2g = (__bf16*)slC;
    __bf16* y3  = (__bf16*)slB;
    __bf16* t1  = (__bf16*)slB;

    // GEMM1: y2g = gelu(GLU(outW · gu + outB))
    gemm_cl_kernel<256, true, false, false, true, 0><<<g4, 256, 0, stream>>>(
        gu_cl, nullptr, nullptr, WpO, outB, nullptr, nullptr, nullptr, nullptr,
        nullptr, nullptr, nullptr, y2g);
    // GEMM2: y3 = lin1 · y2g + lin1b
    gemm_cl_kernel<256, false, false, false, false, 0><<<g2, 256, 0, stream>>>(
        y2g, nullptr, nullptr, WpL, lin1b, nullptr, nullptr, nullptr, nullptr,
        nullptr, nullptr, nullptr, y3);
    // GEMM3: A_cl = x + GLU(gluW · [x_cl; y3] + glub)
    gemm_cl_kernel<512, true, true, false, false, 1><<<g4, 256, 0, stream>>>(
        x_cl, y3, nullptr, WpG, glub, nullptr, nullptr, nullptr, nullptr,
        nullptr, x_cl, A_cl, nullptr);
    ln_stats_cl_kernel<<<16384, 256, 0, stream>>>(A_cl, mu2, rs2);
    // GEMM4: t1 = gelu(ff2a · LN2(A) + ff2ab)
    gemm_cl_kernel<256, false, false, true, true, 0><<<g2, 256, 0, stream>>>(
        nullptr, nullptr, A_cl, WpA, ff2ab, mu2, rs2, ln2g, ln2b,
        nullptr, nullptr, nullptr, t1);
    // GEMM5: out = A + ff2b · t1 + ff2bb   (fp32 [B][H][T])
    gemm_cl_kernel<256, false, false, false, false, 2><<<g2, 256, 0, stream>>>(
        t1, nullptr, nullptr, WpB, ff2bb, nullptr, nullptr, nullptr, nullptr,
        A_cl, nullptr, out, nullptr);
}

// Round 5
// 422.174 us; speedup vs baseline: 1.2018x; 1.2018x over previous
//
#include <hip/hip_runtime.h>
#include <math.h>

// S4D block, MI355X round 5: pair-split scan (8 states/thread, 64-elem chunks).
// B=8, H=256, T=8192, N=16 complex states.

#define TN 8192
#define HN 256
#define BN 8
#define NS 16

typedef __bf16 bf16x8 __attribute__((ext_vector_type(8)));
typedef __bf16 bf16x4 __attribute__((ext_vector_type(4)));
typedef __bf16 bf16x2 __attribute__((ext_vector_type(2)));
typedef float  f32x4  __attribute__((ext_vector_type(4)));

__device__ __forceinline__ float gelu_f(float v) {
    return 0.5f * v * (1.f + erff(v * 0.70710678118654752440f));
}
__device__ __forceinline__ float sigm_f(float v) {
    return 1.f / (1.f + expf(-v));
}

// ---------------- SSM constant prep: store dt*A + 2*Cmod ----------------
__global__ void prep_kernel(const float* __restrict__ log_dt,
                            const float* __restrict__ C_re,
                            const float* __restrict__ C_im,
                            const float* __restrict__ log_A_real,
                            const float* __restrict__ A_imag,
                            float* __restrict__ P)
{
    int i = blockIdx.x * 64 + threadIdx.x;   // 0..4095
    int h = i >> 4;
    float dt = expf(log_dt[h]);
    float Ar = -expf(log_A_real[i]);
    float Ai = A_imag[i];
    float dar = Ar * dt, dai = Ai * dt;
    float er = expf(dar);
    float ar = er * cosf(dai);
    float ai = er * sinf(dai);
    float Er = ar - 1.f, Ei = ai;
    float inv = 1.f / (Ar * Ar + Ai * Ai);
    float Fr = (Er * Ar + Ei * Ai) * inv;
    float Fi = (Ei * Ar - Er * Ai) * inv;
    float cr = C_re[i] * Fr - C_im[i] * Fi;
    float ci = C_re[i] * Fi + C_im[i] * Fr;
    P[i]           = dar;
    P[4096 + i]    = dai;
    P[2*4096 + i]  = 2.f * cr;
    P[3*4096 + i]  = 2.f * ci;
}

// ---------------- weight prep: fp32 -> bf16, tiled+swizzled LDS image ----------------
__global__ void prep_w_kernel(const float* __restrict__ W, __bf16* __restrict__ Wp,
                              int K, int glu)
{
    int id = blockIdx.x * 256 + threadIdx.x;
    int nK = K >> 6;
    int c = id >> 10, r = (id >> 3) & 127, s = id & 7;
    int mt = c / nK, kt = c - mt * nK;
    int R = mt * 128 + r;
    int row = glu ? ((R & 1) ? (R >> 1) + 256 : (R >> 1)) : R;
    int k = kt * 64 + ((s ^ (r & 7)) << 3);
    const float* src = W + (size_t)row * K + k;
    __bf16 o[8];
    #pragma unroll
    for (int j = 0; j < 8; ++j) o[j] = (__bf16)src[j];
    *(uint4*)(Wp + (size_t)id * 8) = *(uint4*)o;
}

// ---------------- channel-LN stats for [B][H][T] fp32 ----------------
__global__ __launch_bounds__(256) void ln_stats_kernel(const float* __restrict__ X,
                                                       float* __restrict__ mu,
                                                       float* __restrict__ rs)
{
    int b = blockIdx.y;
    int t = blockIdx.x * 256 + threadIdx.x;
    const float* p = X + (size_t)b * HN * TN + t;
    float s = 0.f, ss = 0.f;
    #pragma unroll 8
    for (int c = 0; c < HN; ++c) {
        float v = p[(size_t)c * TN];
        s += v; ss += v * v;
    }
    float m = s * (1.f / HN);
    float var = ss * (1.f / HN) - m * m;
    mu[b * TN + t] = m;
    rs[b * TN + t] = rsqrtf(var + 1e-5f);
}

// ---------------- channel-LN stats for [B][T][H] fp32 (channels-last) ----------------
__global__ __launch_bounds__(256) void ln_stats_cl_kernel(const float* __restrict__ A,
                                                          float* __restrict__ mu,
                                                          float* __restrict__ rs)
{
    int row = blockIdx.x * 4 + (threadIdx.x >> 6);   // b*T + t
    int l = threadIdx.x & 63;
    float4 v = *(const float4*)(A + ((size_t)row << 8) + l * 4);
    float s  = v.x + v.y + v.z + v.w;
    float ss = v.x*v.x + v.y*v.y + v.z*v.z + v.w*v.w;
    #pragma unroll
    for (int d = 32; d; d >>= 1) { s += __shfl_down(s, d, 64); ss += __shfl_down(ss, d, 64); }
    if (l == 0) {
        float m = s * (1.f / 256.f);
        mu[row] = m;
        rs[row] = rsqrtf(ss * (1.f / 256.f) - m * m + 1e-5f);
    }
}

// ---------------- transpose [B][H][T] (f32 or bf16) -> [B][T][H] bf16 ----------------
template<typename TI>
__global__ __launch_bounds__(256) void transpose_kernel(const TI* __restrict__ in,
                                                        __bf16* __restrict__ out)
{
    __shared__ float tile[64][65];
    int b = blockIdx.z, h0 = blockIdx.y * 64, t0 = blockIdx.x * 64;
    int tid = threadIdx.x;
    int hl = tid >> 2, pr = tid & 3;
    const TI* src = in + ((size_t)(b * HN + h0 + hl)) * TN + t0 + pr * 16;
    if constexpr (sizeof(TI) == 4) {
        #pragma unroll
        for (int j = 0; j < 4; ++j) {
            float4 v = *(const float4*)((const float*)src + j * 4);
            *(float4*)&tile[hl][pr * 16 + j * 4] = v;
        }
    } else {
        #pragma unroll
        for (int p = 0; p < 2; ++p) {
            bf16x8 v = *(const bf16x8*)((const __bf16*)src + p * 8);
            #pragma unroll
            for (int j = 0; j < 8; ++j) tile[hl][pr * 16 + p * 8 + j] = (float)v[j];
        }
    }
    __syncthreads();
    int tl = tid >> 2;
    __bf16 o[16];
    #pragma unroll
    for (int j = 0; j < 16; ++j) o[j] = (__bf16)tile[pr * 16 + j][tl];
    __bf16* dst = out + ((size_t)(b * TN + t0 + tl)) * HN + h0 + pr * 16;
    *(uint4*)dst = *(uint4*)&o[0];
    *(uint4*)(dst + 8) = *(uint4*)&o[8];
}

// ---------------- S4D scan, pair-split: thread pair (2c,2c+1) owns chunk c (64 elems),
// even lane states 0-7, odd lane states 8-15. Phase 1 computes local scan AND u_loc
// (pair-combined via shfl_xor, overwrites y in LDS). Phase 2 adds the carry term
// Re(c2 * a^(j+1) * s_init) via z <- z*a iteration, gelu, write.
__global__ __launch_bounds__(256, 4) void scan_kernel(const float* __restrict__ X,
                                                      const float* __restrict__ mu,
                                                      const float* __restrict__ rs,
                                                      const float* __restrict__ g1,
                                                      const float* __restrict__ b1,
                                                      const float* __restrict__ Dp,
                                                      const float* __restrict__ P,
                                                      __bf16* __restrict__ GU)
{
    __shared__ float ylds[128 * 68];       // 34816B, pitch-68 per 64-chunk
    __shared__ float astab[16][2];         // a^1
    __shared__ float c2tab[16][2];         // 2*Cmod
    __shared__ float ksd[6][16][2];        // a^(64*2^k), k=0..5 (k=5 -> a^2048)
    __shared__ float wtot[4][16][2];
    int row = blockIdx.x;
    int b = row >> 8, h = row & 255;
    int tid = threadIdx.x;
    int w = tid >> 6, lane = tid & 63;
    int c = tid >> 1;        // chunk 0..127
    int half = tid & 1;      // state half
    int cw = lane >> 1;      // chunk within wave 0..31
    int nb = half * 8;

    float gh = g1[h], bh = b1[h], dh = Dp[h];
    const float* xrow = X + (size_t)(b * HN + h) * TN;
    const float* mup = mu + b * TN;
    const float* rsp = rs + b * TN;

    // ---- tables (direct exponentials, no squaring-error accumulation) ----
    if (tid < 16) {
        int n = tid;
        float dar = P[h * NS + n], dai = P[4096 + h * NS + n];
        float e1 = expf(dar);
        astab[n][0] = e1 * cosf(dai);
        astab[n][1] = e1 * sinf(dai);
        c2tab[n][0] = P[2*4096 + h * NS + n];
        c2tab[n][1] = P[3*4096 + h * NS + n];
        #pragma unroll
        for (int k = 0; k < 6; ++k) {
            float m = (float)(64 << k);
            float er = expf(m * dar);
            float ph = m * dai;
            ksd[k][n][0] = er * cosf(ph);
            ksd[k][n][1] = er * sinf(ph);
        }
    }

    // ---- stage row + inline LN1 (coalesced float4) ----
    #pragma unroll 2
    for (int s = 0; s < 8; ++s) {
        int t = (s * 256 + tid) * 4;
        float4 xv = *(const float4*)(xrow + t);
        float4 m4 = *(const float4*)(mup + t);
        float4 r4 = *(const float4*)(rsp + t);
        float* dst = &ylds[(t >> 6) * 68 + (t & 63)];
        dst[0] = fmaf((xv.x - m4.x) * r4.x, gh, bh);
        dst[1] = fmaf((xv.y - m4.y) * r4.y, gh, bh);
        dst[2] = fmaf((xv.z - m4.z) * r4.z, gh, bh);
        dst[3] = fmaf((xv.w - m4.w) * r4.w, gh, bh);
    }
    __syncthreads();

    float ar[8], ai[8], c2r[8], c2i[8];
    #pragma unroll
    for (int n = 0; n < 8; ++n) {
        ar[n] = astab[nb + n][0]; ai[n] = astab[nb + n][1];
        c2r[n] = c2tab[nb + n][0]; c2i[n] = c2tab[nb + n][1];
    }

    // ---- phase 1: local chunk scan + u_loc (overwrites y slot) ----
    float sr[8], si[8];
    #pragma unroll
    for (int n = 0; n < 8; ++n) { sr[n] = 0.f; si[n] = 0.f; }
    float* yc = &ylds[c * 68];
    #pragma unroll 2
    for (int j = 0; j < 64; ++j) {
        float y = yc[j];
        float up = 0.f;
        #pragma unroll
        for (int n = 0; n < 8; ++n) {
            float nr = fmaf(ar[n], sr[n], fmaf(-ai[n], si[n], y));
            float ni = fmaf(ar[n], si[n], ai[n] * sr[n]);
            sr[n] = nr; si[n] = ni;
            up = fmaf(c2r[n], nr, fmaf(-c2i[n], ni, up));
        }
        float ut = up + __shfl_xor(up, 1, 64);
        if (!half) yc[j] = fmaf(dh, y, ut);
    }

    // ---- Kogge-Stone over chunks within wave (shift 2d lanes = d chunks) ----
    #pragma unroll
    for (int k = 0; k < 5; ++k) {
        int d = 1 << k;
        #pragma unroll
        for (int n = 0; n < 8; ++n) {
            float qpr = __shfl_up(sr[n], (unsigned)(2 * d), 64);
            float qpi = __shfl_up(si[n], (unsigned)(2 * d), 64);
            if (cw >= d) {
                float pdr = ksd[k][nb + n][0], pdi = ksd[k][nb + n][1];
                float nqr = fmaf(pdr, qpr, fmaf(-pdi, qpi, sr[n]));
                float nqi = fmaf(pdr, qpi, fmaf(pdi, qpr, si[n]));
                sr[n] = nqr; si[n] = nqi;
            }
        }
    }
    if (cw == 31) {
        #pragma unroll
        for (int n = 0; n < 8; ++n) { wtot[w][nb + n][0] = sr[n]; wtot[w][nb + n][1] = si[n]; }
    }
    __syncthreads();

    // ---- s_init per chunk, then z = c2 * s_init ----
    float zr[8], zi[8];
    #pragma unroll
    for (int n = 0; n < 8; ++n) {
        float Lr = __shfl_up(sr[n], 2u, 64);
        float Li = __shfl_up(si[n], 2u, 64);
        if (cw == 0) { Lr = 0.f; Li = 0.f; }
        float Sr = 0.f, Si = 0.f;
        float d5r = ksd[5][nb + n][0], d5i = ksd[5][nb + n][1];
        for (int v = 0; v < w; ++v) {
            float tr = fmaf(d5r, Sr, fmaf(-d5i, Si, wtot[v][nb + n][0]));
            float ti = fmaf(d5r, Si, fmaf(d5i, Sr, wtot[v][nb + n][1]));
            Sr = tr; Si = ti;
        }
        float qr = 1.f, qi = 0.f;
        #pragma unroll
        for (int k = 0; k < 5; ++k) {
            if ((cw >> k) & 1) {
                float kr = ksd[k][nb + n][0], ki = ksd[k][nb + n][1];
                float t2 = qr * kr - qi * ki; qi = qr * ki + qi * kr; qr = t2;
            }
        }
        float s0r = qr * Sr - qi * Si + Lr;
        float s0i = qr * Si + qi * Sr + Li;
        zr[n] = c2r[n] * s0r - c2i[n] * s0i;
        zi[n] = c2r[n] * s0i + c2i[n] * s0r;
    }

    // ---- phase 2: u = u_loc + Re(z * a^(j+1)); gelu; back into LDS ----
    float* yw = &ylds[c * 68];
    #pragma unroll 2
    for (int j = 0; j < 64; ++j) {
        float cp = 0.f;
        #pragma unroll
        for (int n = 0; n < 8; ++n) {
            float t2 = zr[n] * ar[n] - zi[n] * ai[n];
            zi[n] = fmaf(zr[n], ai[n], zi[n] * ar[n]);
            zr[n] = t2;
            cp += zr[n];
        }
        float ct = cp + __shfl_xor(cp, 1, 64);
        if ((j & 1) == half) yw[j] = gelu_f(yw[j] + ct);
    }
    __syncthreads();

    // ---- coalesced bf16 write ----
    __bf16* gout = GU + (size_t)(b * HN + h) * TN;
    #pragma unroll 2
    for (int s = 0; s < 8; ++s) {
        int t = (s * 256 + tid) * 4;
        const float* src = &ylds[(t >> 6) * 68 + (t & 63)];
        bf16x4 ov;
        ov[0] = (__bf16)src[0]; ov[1] = (__bf16)src[1];
        ov[2] = (__bf16)src[2]; ov[3] = (__bf16)src[3];
        *(bf16x4*)(gout + t) = ov;
    }
}

// ---------------- MFMA conv1x1 GEMM, channels-last ----------------
// OMODE 0: bf16 out [B][T][H];  1: fp32 A_cl [B][T][H] = GLU + bf16 resB (cl), LDS-transposed;
// OMODE 2: fp32 out [B][H][T] += resF (fp32 cl), LDS-transposed store.
template<int K, bool GLU, bool CONCAT, bool LNIN, bool GELUOUT, int OMODE>
__global__ __launch_bounds__(256) void gemm_cl_kernel(
    const __bf16* __restrict__ B0, const __bf16* __restrict__ B1,
    const float*  __restrict__ BF,
    const __bf16* __restrict__ Wp, const float* __restrict__ bias,
    const float* __restrict__ mu, const float* __restrict__ rsd,
    const float* __restrict__ lng, const float* __restrict__ lnb,
    const float* __restrict__ resF, const __bf16* __restrict__ resB,
    float* __restrict__ outF, __bf16* __restrict__ outB)
{
    constexpr int nK = K / 64;
    constexpr int LDSSZ = (OMODE != 0) ? 34816 : 32768;
    __shared__ __align__(16) char lds[LDSSZ];
    char* sA = lds;
    char* sB = lds + 16384;
    int tid = threadIdx.x;
    int w = tid >> 6, wr = w >> 1, wc = w & 1;
    int b = blockIdx.z, by = blockIdx.y;
    int t0 = blockIdx.x * 128;
    int lane = tid & 63;
    int lr = tid & 15, lg = (tid >> 4) & 3;
    int rl = lane >> 3, sl = lane & 7;

    f32x4 acc[4][4];
    #pragma unroll
    for (int i = 0; i < 4; ++i)
        #pragma unroll
        for (int j = 0; j < 4; ++j) acc[i][j] = (f32x4){0.f, 0.f, 0.f, 0.f};

    for (int kt = 0; kt < nK; ++kt) {
        {
            const char* asrc = (const char*)Wp + (((size_t)by * nK + kt) << 14)
                               + w * 4096 + lane * 16;
            char* adst = sA + w * 4096;
            #pragma unroll
            for (int i = 0; i < 4; ++i)
                __builtin_amdgcn_global_load_lds(
                    (const __attribute__((address_space(1))) void*)(asrc + i * 1024),
                    (__attribute__((address_space(3))) void*)(adst + i * 1024), 16, 0, 0);
        }
        if constexpr (!LNIN) {
            int kg = kt * 64;
            const __bf16* base = (CONCAT && kg >= 256) ? B1 : B0;
            int kloc = (CONCAT && kg >= 256) ? kg - 256 : kg;
            #pragma unroll
            for (int i = 0; i < 4; ++i) {
                int rb = w * 32 + i * 8 + rl;
                const char* gs = (const char*)(base + (((size_t)(b * TN + t0 + rb)) << 8) + kloc)
                                 + ((sl ^ rl) << 4);
                __builtin_amdgcn_global_load_lds(
                    (const __attribute__((address_space(1))) void*)gs,
                    (__attribute__((address_space(3))) void*)(sB + w * 4096 + i * 1024), 16, 0, 0);
            }
        } else {
            #pragma unroll
            for (int i = 0; i < 8; ++i) {
                int q = i * 256 + tid;
                int r = q >> 4, qs = q & 15;
                int t = t0 + r;
                const float* src = BF + (((size_t)(b * TN + t)) << 8) + kt * 64 + qs * 4;
                float4 v = *(const float4*)src;
                float m_ = mu[b * TN + t], rr = rsd[b * TN + t];
                float4 g4 = *(const float4*)(lng + kt * 64 + qs * 4);
                float4 b4 = *(const float4*)(lnb + kt * 64 + qs * 4);
                __bf16 o[4];
                o[0] = (__bf16)fmaf((v.x - m_) * rr, g4.x, b4.x);
                o[1] = (__bf16)fmaf((v.y - m_) * rr, g4.y, b4.y);
                o[2] = (__bf16)fmaf((v.z - m_) * rr, g4.z, b4.z);
                o[3] = (__bf16)fmaf((v.w - m_) * rr, g4.w, b4.w);
                int off = r * 128 + ((((qs >> 1) ^ (r & 7))) << 4) + (qs & 1) * 8;
                *(uint2*)(sB + off) = *(uint2*)o;
            }
        }
        __syncthreads();

        const char* aB = sA + (wr * 64 + lr) * 128;
        const char* bB = sB + (wc * 64 + lr) * 128;
        int swz = (lr & 7) << 4;
        #pragma unroll
        for (int ks = 0; ks < 2; ++ks) {
            int ko = (ks * 64 + lg * 16) ^ swz;
            bf16x8 af[4], bfr[4];
            #pragma unroll
            for (int f = 0; f < 4; ++f) af[f]  = *(const bf16x8*)(aB + f * 2048 + ko);
            #pragma unroll
            for (int f = 0; f < 4; ++f) bfr[f] = *(const bf16x8*)(bB + f * 2048 + ko);
            #pragma unroll
            for (int fm = 0; fm < 4; ++fm)
                #pragma unroll
                for (int fn = 0; fn < 4; ++fn)
                    acc[fm][fn] = __builtin_amdgcn_mfma_f32_16x16x32_bf16(
                        af[fm], bfr[fn], acc[fm][fn], 0, 0, 0);
        }
        __syncthreads();
    }

    int tcb = t0 + wc * 64 + lr;
    int mrow0 = by * 128 + wr * 64 + lg * 4;

    if constexpr (OMODE == 1) {
        float* tile = (float*)lds;
        #pragma unroll
        for (int fm = 0; fm < 4; ++fm) {
            int R0 = mrow0 + fm * 16;
            int c_ = R0 >> 1;
            int cloc = c_ - by * 64;
            #pragma unroll
            for (int fn = 0; fn < 4; ++fn) {
                f32x4 v = acc[fm][fn];
                float a0 = v[0] + bias[c_],     g0 = v[1] + bias[c_ + 256];
                float a1 = v[2] + bias[c_ + 1], g1 = v[3] + bias[c_ + 257];
                float o0 = a0 * sigm_f(g0), o1 = a1 * sigm_f(g1);
                if constexpr (GELUOUT) { o0 = gelu_f(o0); o1 = gelu_f(o1); }
                int tl = wc * 64 + lr + fn * 16;
                *(float2*)&tile[tl * 68 + cloc] = make_float2(o0, o1);
            }
        }
        __syncthreads();
        #pragma unroll
        for (int it = 0; it < 8; ++it) {
            int fid = it * 256 + tid;
            int tl = fid >> 4, f = (fid & 15) << 2;
            size_t go = (((size_t)(b * TN + t0 + tl)) << 8) + by * 64 + f;
            float4 v = *(const float4*)&tile[tl * 68 + f];
            bf16x4 xr = *(const bf16x4*)(resB + go);
            v.x += (float)xr[0]; v.y += (float)xr[1];
            v.z += (float)xr[2]; v.w += (float)xr[3];
            *(float4*)(outF + go) = v;
        }
    } else if constexpr (OMODE == 2) {
        float* tile = (float*)lds;
        #pragma unroll
        for (int ht = 0; ht < 2; ++ht) {
            if (wc == ht) {
                #pragma unroll
                for (int fm = 0; fm < 4; ++fm) {
                    int R0 = mrow0 + fm * 16;
                    int mloc = R0 - by * 128;
                    #pragma unroll
                    for (int fn = 0; fn < 4; ++fn) {
                        int t = tcb + fn * 16;
                        f32x4 v = acc[fm][fn];
                        float4 rv = *(const float4*)(resF + (((size_t)(b * TN + t)) << 8) + R0);
                        int tloc = lr + fn * 16;
                        tile[(mloc + 0) * 68 + tloc] = v[0] + bias[R0 + 0] + rv.x;
                        tile[(mloc + 1) * 68 + tloc] = v[1] + bias[R0 + 1] + rv.y;
                        tile[(mloc + 2) * 68 + tloc] = v[2] + bias[R0 + 2] + rv.z;
                        tile[(mloc + 3) * 68 + tloc] = v[3] + bias[R0 + 3] + rv.w;
                    }
                }
            }
            __syncthreads();
            #pragma unroll
            for (int it = 0; it < 8; ++it) {
                int fid = it * 256 + tid;
                int m = fid >> 4, f = (fid & 15) << 2;
                float4 v = *(const float4*)&tile[m * 68 + f];
                *(float4*)(outF + ((size_t)(b * HN + by * 128 + m)) * TN + t0 + ht * 64 + f) = v;
            }
            __syncthreads();
        }
    } else {
        #pragma unroll
        for (int fm = 0; fm < 4; ++fm) {
            int R0 = mrow0 + fm * 16;
            #pragma unroll
            for (int fn = 0; fn < 4; ++fn) {
                int t = tcb + fn * 16;
                f32x4 v = acc[fm][fn];
                size_t rowoff = ((size_t)(b * TN + t)) << 8;
                if constexpr (GLU) {
                    int c_ = R0 >> 1;
                    float a0 = v[0] + bias[c_],     g0 = v[1] + bias[c_ + 256];
                    float a1 = v[2] + bias[c_ + 1], g1 = v[3] + bias[c_ + 257];
                    float o0 = a0 * sigm_f(g0), o1 = a1 * sigm_f(g1);
                    if constexpr (GELUOUT) { o0 = gelu_f(o0); o1 = gelu_f(o1); }
                    bf16x2 ov; ov[0] = (__bf16)o0; ov[1] = (__bf16)o1;
                    *(bf16x2*)(outB + rowoff + c_) = ov;
                } else {
                    float vv[4];
                    #pragma unroll
                    for (int j = 0; j < 4; ++j) vv[j] = v[j] + bias[R0 + j];
                    if constexpr (GELUOUT) {
                        #pragma unroll
                        for (int j = 0; j < 4; ++j) vv[j] = gelu_f(vv[j]);
                    }
                    bf16x4 ov;
                    #pragma unroll
                    for (int j = 0; j < 4; ++j) ov[j] = (__bf16)vv[j];
                    *(bf16x4*)(outB + rowoff + R0) = ov;
                }
            }
        }
    }
}

extern "C" void kernel_launch(void* const* d_in, const int* in_sizes, int n_in,
                              void* d_out, int out_size, void* d_ws, size_t ws_size,
                              hipStream_t stream)
{
    (void)in_sizes; (void)n_in; (void)out_size; (void)ws_size;
    const float* x      = (const float*)d_in[0];
    const float* log_dt = (const float*)d_in[1];
    const float* C_re   = (const float*)d_in[2];
    const float* C_im   = (const float*)d_in[3];
    const float* logAr  = (const float*)d_in[4];
    const float* A_im   = (const float*)d_in[5];
    const float* Dp     = (const float*)d_in[6];
    const float* outW   = (const float*)d_in[7];
    const float* outB   = (const float*)d_in[8];
    const float* ln1g   = (const float*)d_in[9];
    const float* ln1b   = (const float*)d_in[10];
    const float* lin1W  = (const float*)d_in[11];
    const float* lin1b  = (const float*)d_in[12];
    const float* gluW   = (const float*)d_in[13];
    const float* glub   = (const float*)d_in[14];
    const float* ln2g   = (const float*)d_in[15];
    const float* ln2b   = (const float*)d_in[16];
    const float* ff2aW  = (const float*)d_in[17];
    const float* ff2ab  = (const float*)d_in[18];
    const float* ff2bW  = (const float*)d_in[19];
    const float* ff2bb  = (const float*)d_in[20];
    float* out = (float*)d_out;

    char* ws = (char*)d_ws;
    const size_t MB = 1u << 20;
    float*  P    = (float*)(ws);
    float*  mu1  = (float*)(ws + 0x40000);
    float*  rs1  = (float*)(ws + 0x80000);
    float*  mu2  = (float*)(ws + 0xC0000);
    float*  rs2  = (float*)(ws + 0x100000);
    __bf16* WpO  = (__bf16*)(ws + 0x140000);
    __bf16* WpL  = (__bf16*)(ws + 0x180000);
    __bf16* WpG  = (__bf16*)(ws + 0x1A0000);
    __bf16* WpA  = (__bf16*)(ws + 0x220000);
    __bf16* WpB  = (__bf16*)(ws + 0x240000);
    __bf16* x_cl = (__bf16*)(ws + 4 * MB);     // 32MB [B][T][H] bf16
    char*   slB  = ws + 36 * MB;               // 32MB
    char*   slC  = ws + 68 * MB;               // 32MB
    float*  A_cl = (float*)(ws + 68 * MB);     // 64MB fp32

    prep_kernel<<<64, 64, 0, stream>>>(log_dt, C_re, C_im, logAr, A_im, P);
    prep_w_kernel<<<64, 256, 0, stream>>>(outW,  WpO, 256, 1);
    prep_w_kernel<<<32, 256, 0, stream>>>(lin1W, WpL, 256, 0);
    prep_w_kernel<<<128, 256, 0, stream>>>(gluW, WpG, 512, 1);
    prep_w_kernel<<<32, 256, 0, stream>>>(ff2aW, WpA, 256, 0);
    prep_w_kernel<<<32, 256, 0, stream>>>(ff2bW, WpB, 256, 0);

    ln_stats_kernel<<<dim3(32, BN), 256, 0, stream>>>(x, mu1, rs1);
    transpose_kernel<float><<<dim3(128, 4, BN), 256, 0, stream>>>(x, x_cl);

    __bf16* gu_raw = (__bf16*)slC;
    __bf16* gu_cl  = (__bf16*)slB;
    scan_kernel<<<2048, 256, 0, stream>>>(x, mu1, rs1, ln1g, ln1b, Dp, P, gu_raw);
    transpose_kernel<__bf16><<<dim3(128, 4, BN), 256, 0, stream>>>(gu_raw, gu_cl);

    dim3 g2(64, 2, BN), g4(64, 4, BN);
    __bf16* y2g = (__bf16*)slC;
    __bf16* y3  = (__bf16*)slB;
    __bf16* t1  = (__bf16*)slB;

    // GEMM1: y2g = gelu(GLU(outW · gu + outB))
    gemm_cl_kernel<256, true, false, false, true, 0><<<g4, 256, 0, stream>>>(
        gu_cl, nullptr, nullptr, WpO, outB, nullptr, nullptr, nullptr, nullptr,
        nullptr, nullptr, nullptr, y2g);
    // GEMM2: y3 = lin1 · y2g + lin1b
    gemm_cl_kernel<256, false, false, false, false, 0><<<g2, 256, 0, stream>>>(
        y2g, nullptr, nullptr, WpL, lin1b, nullptr, nullptr, nullptr, nullptr,
        nullptr, nullptr, nullptr, y3);
    // GEMM3: A_cl = x + GLU(gluW · [x_cl; y3] + glub)
    gemm_cl_kernel<512, true, true, false, false, 1><<<g4, 256, 0, stream>>>(
        x_cl, y3, nullptr, WpG, glub, nullptr, nullptr, nullptr, nullptr,
        nullptr, x_cl, A_cl, nullptr);
    ln_stats_cl_kernel<<<16384, 256, 0, stream>>>(A_cl, mu2, rs2);
    // GEMM4: t1 = gelu(ff2a · LN2(A) + ff2ab)
    gemm_cl_kernel<256, false, false, true, true, 0><<<g2, 256, 0, stream>>>(
        nullptr, nullptr, A_cl, WpA, ff2ab, mu2, rs2, ln2g, ln2b,
        nullptr, nullptr, nullptr, t1);
    // GEMM5: out = A + ff2b · t1 + ff2bb   (fp32 [B][H][T])
    gemm_cl_kernel<256, false, false, false, false, 2><<<g2, 256, 0, stream>>>(
        t1, nullptr, nullptr, WpB, ff2bb, nullptr, nullptr, nullptr, nullptr,
        A_cl, nullptr, out, nullptr);
}

// Round 6
// 396.020 us; speedup vs baseline: 1.2811x; 1.0660x over previous
//
#include <hip/hip_runtime.h>
#include <math.h>

// S4D block, MI355X round 6: scan = full-16-state threads, 32-elem chunks,
// batched scalar LDS (pitch 33), two-pass (summary -> KS -> seeded rescan).
// B=8, H=256, T=8192, N=16 complex states.

#define TN 8192
#define HN 256
#define BN 8
#define NS 16

typedef __bf16 bf16x8 __attribute__((ext_vector_type(8)));
typedef __bf16 bf16x4 __attribute__((ext_vector_type(4)));
typedef __bf16 bf16x2 __attribute__((ext_vector_type(2)));
typedef float  f32x4  __attribute__((ext_vector_type(4)));

__device__ __forceinline__ float gelu_f(float v) {
    return 0.5f * v * (1.f + erff(v * 0.70710678118654752440f));
}
__device__ __forceinline__ float sigm_f(float v) {
    return 1.f / (1.f + expf(-v));
}

// ---------------- SSM constant prep: store dt*A + 2*Cmod ----------------
__global__ void prep_kernel(const float* __restrict__ log_dt,
                            const float* __restrict__ C_re,
                            const float* __restrict__ C_im,
                            const float* __restrict__ log_A_real,
                            const float* __restrict__ A_imag,
                            float* __restrict__ P)
{
    int i = blockIdx.x * 64 + threadIdx.x;   // 0..4095
    int h = i >> 4;
    float dt = expf(log_dt[h]);
    float Ar = -expf(log_A_real[i]);
    float Ai = A_imag[i];
    float dar = Ar * dt, dai = Ai * dt;
    float er = expf(dar);
    float ar = er * cosf(dai);
    float ai = er * sinf(dai);
    float Er = ar - 1.f, Ei = ai;
    float inv = 1.f / (Ar * Ar + Ai * Ai);
    float Fr = (Er * Ar + Ei * Ai) * inv;
    float Fi = (Ei * Ar - Er * Ai) * inv;
    float cr = C_re[i] * Fr - C_im[i] * Fi;
    float ci = C_re[i] * Fi + C_im[i] * Fr;
    P[i]           = dar;
    P[4096 + i]    = dai;
    P[2*4096 + i]  = 2.f * cr;
    P[3*4096 + i]  = 2.f * ci;
}

// ---------------- weight prep: fp32 -> bf16, tiled+swizzled LDS image ----------------
__global__ void prep_w_kernel(const float* __restrict__ W, __bf16* __restrict__ Wp,
                              int K, int glu)
{
    int id = blockIdx.x * 256 + threadIdx.x;
    int nK = K >> 6;
    int c = id >> 10, r = (id >> 3) & 127, s = id & 7;
    int mt = c / nK, kt = c - mt * nK;
    int R = mt * 128 + r;
    int row = glu ? ((R & 1) ? (R >> 1) + 256 : (R >> 1)) : R;
    int k = kt * 64 + ((s ^ (r & 7)) << 3);
    const float* src = W + (size_t)row * K + k;
    __bf16 o[8];
    #pragma unroll
    for (int j = 0; j < 8; ++j) o[j] = (__bf16)src[j];
    *(uint4*)(Wp + (size_t)id * 8) = *(uint4*)o;
}

// ---------------- channel-LN stats for [B][H][T] fp32 ----------------
__global__ __launch_bounds__(256) void ln_stats_kernel(const float* __restrict__ X,
                                                       float* __restrict__ mu,
                                                       float* __restrict__ rs)
{
    int b = blockIdx.y;
    int t = blockIdx.x * 256 + threadIdx.x;
    const float* p = X + (size_t)b * HN * TN + t;
    float s = 0.f, ss = 0.f;
    #pragma unroll 8
    for (int c = 0; c < HN; ++c) {
        float v = p[(size_t)c * TN];
        s += v; ss += v * v;
    }
    float m = s * (1.f / HN);
    float var = ss * (1.f / HN) - m * m;
    mu[b * TN + t] = m;
    rs[b * TN + t] = rsqrtf(var + 1e-5f);
}

// ---------------- channel-LN stats for [B][T][H] fp32 (channels-last) ----------------
__global__ __launch_bounds__(256) void ln_stats_cl_kernel(const float* __restrict__ A,
                                                          float* __restrict__ mu,
                                                          float* __restrict__ rs)
{
    int row = blockIdx.x * 4 + (threadIdx.x >> 6);   // b*T + t
    int l = threadIdx.x & 63;
    float4 v = *(const float4*)(A + ((size_t)row << 8) + l * 4);
    float s  = v.x + v.y + v.z + v.w;
    float ss = v.x*v.x + v.y*v.y + v.z*v.z + v.w*v.w;
    #pragma unroll
    for (int d = 32; d; d >>= 1) { s += __shfl_down(s, d, 64); ss += __shfl_down(ss, d, 64); }
    if (l == 0) {
        float m = s * (1.f / 256.f);
        mu[row] = m;
        rs[row] = rsqrtf(ss * (1.f / 256.f) - m * m + 1e-5f);
    }
}

// ---------------- transpose [B][H][T] (f32 or bf16) -> [B][T][H] bf16 ----------------
template<typename TI>
__global__ __launch_bounds__(256) void transpose_kernel(const TI* __restrict__ in,
                                                        __bf16* __restrict__ out)
{
    __shared__ float tile[64][65];
    int b = blockIdx.z, h0 = blockIdx.y * 64, t0 = blockIdx.x * 64;
    int tid = threadIdx.x;
    int hl = tid >> 2, pr = tid & 3;
    const TI* src = in + ((size_t)(b * HN + h0 + hl)) * TN + t0 + pr * 16;
    if constexpr (sizeof(TI) == 4) {
        #pragma unroll
        for (int j = 0; j < 4; ++j) {
            float4 v = *(const float4*)((const float*)src + j * 4);
            *(float4*)&tile[hl][pr * 16 + j * 4] = v;
        }
    } else {
        #pragma unroll
        for (int p = 0; p < 2; ++p) {
            bf16x8 v = *(const bf16x8*)((const __bf16*)src + p * 8);
            #pragma unroll
            for (int j = 0; j < 8; ++j) tile[hl][pr * 16 + p * 8 + j] = (float)v[j];
        }
    }
    __syncthreads();
    int tl = tid >> 2;
    __bf16 o[16];
    #pragma unroll
    for (int j = 0; j < 16; ++j) o[j] = (__bf16)tile[pr * 16 + j][tl];
    __bf16* dst = out + ((size_t)(b * TN + t0 + tl)) * HN + h0 + pr * 16;
    *(uint4*)dst = *(uint4*)&o[0];
    *(uint4*)(dst + 8) = *(uint4*)&o[8];
}

// ---------------- S4D scan: thread owns chunk of 32 elems, all 16 states ----------------
// Pass A: chunk summary (state-only). KS over 64 lanes (decay a^(32*2^k)),
// block combine over 4 waves (a^2048). Pass B: seeded rescan emits gelu(u).
// LDS pitch 33 -> scalar accesses are 2-way banked (free); reads batched by 8.
__global__ __launch_bounds__(256, 4) void scan_kernel(const float* __restrict__ X,
                                                      const float* __restrict__ mu,
                                                      const float* __restrict__ rs,
                                                      const float* __restrict__ g1,
                                                      const float* __restrict__ b1,
                                                      const float* __restrict__ Dp,
                                                      const float* __restrict__ P,
                                                      __bf16* __restrict__ GU)
{
    __shared__ float ylds[256 * 33];      // 33792B
    __shared__ float astab[16][2];        // a
    __shared__ float c2tab[16][2];        // 2*Cmod
    __shared__ float ksd[7][16][2];       // a^(32*2^k), k=0..6 (k=6 -> a^2048)
    __shared__ float wtot[4][16][2];
    int row = blockIdx.x;
    int b = row >> 8, h = row & 255;
    int tid = threadIdx.x;
    int w = tid >> 6, l = tid & 63;

    float gh = g1[h], bh = b1[h], dh = Dp[h];
    const float* xrow = X + (size_t)(b * HN + h) * TN;
    const float* mup = mu + b * TN;
    const float* rsp = rs + b * TN;

    // ---- tables (direct exponentials) ----
    if (tid < 16) {
        int n = tid;
        float dar = P[h * NS + n], dai = P[4096 + h * NS + n];
        float e1 = expf(dar);
        astab[n][0] = e1 * cosf(dai);
        astab[n][1] = e1 * sinf(dai);
        c2tab[n][0] = P[2*4096 + h * NS + n];
        c2tab[n][1] = P[3*4096 + h * NS + n];
        #pragma unroll
        for (int k = 0; k < 7; ++k) {
            float m = (float)(32 << k);
            float er = expf(m * dar);
            float ph = m * dai;
            ksd[k][n][0] = er * cosf(ph);
            ksd[k][n][1] = er * sinf(ph);
        }
    }

    // ---- stage row + inline LN1 (coalesced global float4, scalar LDS writes) ----
    #pragma unroll 2
    for (int s = 0; s < 8; ++s) {
        int t = (s * 256 + tid) * 4;
        float4 xv = *(const float4*)(xrow + t);
        float4 m4 = *(const float4*)(mup + t);
        float4 r4 = *(const float4*)(rsp + t);
        float* dst = &ylds[(t >> 5) * 33 + (t & 31)];
        dst[0] = fmaf((xv.x - m4.x) * r4.x, gh, bh);
        dst[1] = fmaf((xv.y - m4.y) * r4.y, gh, bh);
        dst[2] = fmaf((xv.z - m4.z) * r4.z, gh, bh);
        dst[3] = fmaf((xv.w - m4.w) * r4.w, gh, bh);
    }
    __syncthreads();

    float ar_[16], ai_[16];
    #pragma unroll
    for (int n = 0; n < 16; ++n) { ar_[n] = astab[n][0]; ai_[n] = astab[n][1]; }

    // ---- pass A: chunk summary ----
    float sr[16], si[16];
    #pragma unroll
    for (int n = 0; n < 16; ++n) { sr[n] = 0.f; si[n] = 0.f; }
    const float* yc = &ylds[tid * 33];
    #pragma unroll 1
    for (int g = 0; g < 4; ++g) {
        float yv[8];
        #pragma unroll
        for (int e = 0; e < 8; ++e) yv[e] = yc[g * 8 + e];
        #pragma unroll
        for (int e = 0; e < 8; ++e) {
            float y = yv[e];
            #pragma unroll
            for (int n = 0; n < 16; ++n) {
                float nr = fmaf(ar_[n], sr[n], fmaf(-ai_[n], si[n], y));
                si[n] = fmaf(ar_[n], si[n], ai_[n] * sr[n]);
                sr[n] = nr;
            }
        }
    }

    // ---- Kogge-Stone over 64 chunks in wave ----
    #pragma unroll
    for (int k = 0; k < 6; ++k) {
        int d = 1 << k;
        #pragma unroll
        for (int n = 0; n < 16; ++n) {
            float qpr = __shfl_up(sr[n], (unsigned)d, 64);
            float qpi = __shfl_up(si[n], (unsigned)d, 64);
            if (l >= d) {
                float pdr = ksd[k][n][0], pdi = ksd[k][n][1];
                sr[n] = fmaf(pdr, qpr, fmaf(-pdi, qpi, sr[n]));
                si[n] = fmaf(pdr, qpi, fmaf(pdi, qpr, si[n]));
            }
        }
    }
    if (l == 63) {
        #pragma unroll
        for (int n = 0; n < 16; ++n) { wtot[w][n][0] = sr[n]; wtot[w][n][1] = si[n]; }
    }
    __syncthreads();

    // ---- s_init per chunk ----
    #pragma unroll
    for (int n = 0; n < 16; ++n) {
        float Lr = __shfl_up(sr[n], 1u, 64);
        float Li = __shfl_up(si[n], 1u, 64);
        if (l == 0) { Lr = 0.f; Li = 0.f; }
        float Sr = 0.f, Si = 0.f;
        float d6r = ksd[6][n][0], d6i = ksd[6][n][1];
        for (int v = 0; v < w; ++v) {
            float tr = fmaf(d6r, Sr, fmaf(-d6i, Si, wtot[v][n][0]));
            float ti = fmaf(d6r, Si, fmaf(d6i, Sr, wtot[v][n][1]));
            Sr = tr; Si = ti;
        }
        float qr = 1.f, qi = 0.f;
        #pragma unroll
        for (int k = 0; k < 6; ++k) {
            if ((l >> k) & 1) {
                float kr = ksd[k][n][0], ki = ksd[k][n][1];
                float t2 = qr * kr - qi * ki;
                qi = fmaf(qr, ki, qi * kr);
                qr = t2;
            }
        }
        sr[n] = fmaf(qr, Sr, fmaf(-qi, Si, Lr));
        si[n] = fmaf(qr, Si, fmaf(qi, Sr, Li));
    }

    float c2r_[16], c2i_[16];
    #pragma unroll
    for (int n = 0; n < 16; ++n) { c2r_[n] = c2tab[n][0]; c2i_[n] = c2tab[n][1]; }

    // ---- pass B: seeded rescan, emit gelu(u) in place ----
    float* yw = &ylds[tid * 33];
    #pragma unroll 1
    for (int g = 0; g < 4; ++g) {
        float yv[8];
        #pragma unroll
        for (int e = 0; e < 8; ++e) yv[e] = yw[g * 8 + e];
        #pragma unroll
        for (int e = 0; e < 8; ++e) {
            float y = yv[e];
            float u = dh * y;
            #pragma unroll
            for (int n = 0; n < 16; ++n) {
                float nr = fmaf(ar_[n], sr[n], fmaf(-ai_[n], si[n], y));
                si[n] = fmaf(ar_[n], si[n], ai_[n] * sr[n]);
                sr[n] = nr;
                u = fmaf(c2r_[n], nr, fmaf(-c2i_[n], si[n], u));
            }
            yw[g * 8 + e] = gelu_f(u);
        }
    }
    __syncthreads();

    // ---- coalesced bf16 write ----
    __bf16* gout = GU + (size_t)(b * HN + h) * TN;
    #pragma unroll 2
    for (int s = 0; s < 8; ++s) {
        int t = (s * 256 + tid) * 4;
        const float* src = &ylds[(t >> 5) * 33 + (t & 31)];
        bf16x4 ov;
        ov[0] = (__bf16)src[0]; ov[1] = (__bf16)src[1];
        ov[2] = (__bf16)src[2]; ov[3] = (__bf16)src[3];
        *(bf16x4*)(gout + t) = ov;
    }
}

// ---------------- MFMA conv1x1 GEMM, channels-last ----------------
// OMODE 0: bf16 out [B][T][H];  1: fp32 A_cl [B][T][H] = GLU + bf16 resB (cl), LDS-transposed;
// OMODE 2: fp32 out [B][H][T] += resF (fp32 cl), LDS-transposed store.
template<int K, bool GLU, bool CONCAT, bool LNIN, bool GELUOUT, int OMODE>
__global__ __launch_bounds__(256) void gemm_cl_kernel(
    const __bf16* __restrict__ B0, const __bf16* __restrict__ B1,
    const float*  __restrict__ BF,
    const __bf16* __restrict__ Wp, const float* __restrict__ bias,
    const float* __restrict__ mu, const float* __restrict__ rsd,
    const float* __restrict__ lng, const float* __restrict__ lnb,
    const float* __restrict__ resF, const __bf16* __restrict__ resB,
    float* __restrict__ outF, __bf16* __restrict__ outB)
{
    constexpr int nK = K / 64;
    constexpr int LDSSZ = (OMODE != 0) ? 34816 : 32768;
    __shared__ __align__(16) char lds[LDSSZ];
    char* sA = lds;
    char* sB = lds + 16384;
    int tid = threadIdx.x;
    int w = tid >> 6, wr = w >> 1, wc = w & 1;
    int b = blockIdx.z, by = blockIdx.y;
    int t0 = blockIdx.x * 128;
    int lane = tid & 63;
    int lr = tid & 15, lg = (tid >> 4) & 3;
    int rl = lane >> 3, sl = lane & 7;

    f32x4 acc[4][4];
    #pragma unroll
    for (int i = 0; i < 4; ++i)
        #pragma unroll
        for (int j = 0; j < 4; ++j) acc[i][j] = (f32x4){0.f, 0.f, 0.f, 0.f};

    for (int kt = 0; kt < nK; ++kt) {
        {
            const char* asrc = (const char*)Wp + (((size_t)by * nK + kt) << 14)
                               + w * 4096 + lane * 16;
            char* adst = sA + w * 4096;
            #pragma unroll
            for (int i = 0; i < 4; ++i)
                __builtin_amdgcn_global_load_lds(
                    (const __attribute__((address_space(1))) void*)(asrc + i * 1024),
                    (__attribute__((address_space(3))) void*)(adst + i * 1024), 16, 0, 0);
        }
        if constexpr (!LNIN) {
            int kg = kt * 64;
            const __bf16* base = (CONCAT && kg >= 256) ? B1 : B0;
            int kloc = (CONCAT && kg >= 256) ? kg - 256 : kg;
            #pragma unroll
            for (int i = 0; i < 4; ++i) {
                int rb = w * 32 + i * 8 + rl;
                const char* gs = (const char*)(base + (((size_t)(b * TN + t0 + rb)) << 8) + kloc)
                                 + ((sl ^ rl) << 4);
                __builtin_amdgcn_global_load_lds(
                    (const __attribute__((address_space(1))) void*)gs,
                    (__attribute__((address_space(3))) void*)(sB + w * 4096 + i * 1024), 16, 0, 0);
            }
        } else {
            #pragma unroll
            for (int i = 0; i < 8; ++i) {
                int q = i * 256 + tid;
                int r = q >> 4, qs = q & 15;
                int t = t0 + r;
                const float* src = BF + (((size_t)(b * TN + t)) << 8) + kt * 64 + qs * 4;
                float4 v = *(const float4*)src;
                float m_ = mu[b * TN + t], rr = rsd[b * TN + t];
                float4 g4 = *(const float4*)(lng + kt * 64 + qs * 4);
                float4 b4 = *(const float4*)(lnb + kt * 64 + qs * 4);
                __bf16 o[4];
                o[0] = (__bf16)fmaf((v.x - m_) * rr, g4.x, b4.x);
                o[1] = (__bf16)fmaf((v.y - m_) * rr, g4.y, b4.y);
                o[2] = (__bf16)fmaf((v.z - m_) * rr, g4.z, b4.z);
                o[3] = (__bf16)fmaf((v.w - m_) * rr, g4.w, b4.w);
                int off = r * 128 + ((((qs >> 1) ^ (r & 7))) << 4) + (qs & 1) * 8;
                *(uint2*)(sB + off) = *(uint2*)o;
            }
        }
        __syncthreads();

        const char* aB = sA + (wr * 64 + lr) * 128;
        const char* bB = sB + (wc * 64 + lr) * 128;
        int swz = (lr & 7) << 4;
        #pragma unroll
        for (int ks = 0; ks < 2; ++ks) {
            int ko = (ks * 64 + lg * 16) ^ swz;
            bf16x8 af[4], bfr[4];
            #pragma unroll
            for (int f = 0; f < 4; ++f) af[f]  = *(const bf16x8*)(aB + f * 2048 + ko);
            #pragma unroll
            for (int f = 0; f < 4; ++f) bfr[f] = *(const bf16x8*)(bB + f * 2048 + ko);
            #pragma unroll
            for (int fm = 0; fm < 4; ++fm)
                #pragma unroll
                for (int fn = 0; fn < 4; ++fn)
                    acc[fm][fn] = __builtin_amdgcn_mfma_f32_16x16x32_bf16(
                        af[fm], bfr[fn], acc[fm][fn], 0, 0, 0);
        }
        __syncthreads();
    }

    int tcb = t0 + wc * 64 + lr;
    int mrow0 = by * 128 + wr * 64 + lg * 4;

    if constexpr (OMODE == 1) {
        float* tile = (float*)lds;
        #pragma unroll
        for (int fm = 0; fm < 4; ++fm) {
            int R0 = mrow0 + fm * 16;
            int c_ = R0 >> 1;
            int cloc = c_ - by * 64;
            #pragma unroll
            for (int fn = 0; fn < 4; ++fn) {
                f32x4 v = acc[fm][fn];
                float a0 = v[0] + bias[c_],     g0 = v[1] + bias[c_ + 256];
                float a1 = v[2] + bias[c_ + 1], g1 = v[3] + bias[c_ + 257];
                float o0 = a0 * sigm_f(g0), o1 = a1 * sigm_f(g1);
                if constexpr (GELUOUT) { o0 = gelu_f(o0); o1 = gelu_f(o1); }
                int tl = wc * 64 + lr + fn * 16;
                *(float2*)&tile[tl * 68 + cloc] = make_float2(o0, o1);
            }
        }
        __syncthreads();
        #pragma unroll
        for (int it = 0; it < 8; ++it) {
            int fid = it * 256 + tid;
            int tl = fid >> 4, f = (fid & 15) << 2;
            size_t go = (((size_t)(b * TN + t0 + tl)) << 8) + by * 64 + f;
            float4 v = *(const float4*)&tile[tl * 68 + f];
            bf16x4 xr = *(const bf16x4*)(resB + go);
            v.x += (float)xr[0]; v.y += (float)xr[1];
            v.z += (float)xr[2]; v.w += (float)xr[3];
            *(float4*)(outF + go) = v;
        }
    } else if constexpr (OMODE == 2) {
        float* tile = (float*)lds;
        #pragma unroll
        for (int ht = 0; ht < 2; ++ht) {
            if (wc == ht) {
                #pragma unroll
                for (int fm = 0; fm < 4; ++fm) {
                    int R0 = mrow0 + fm * 16;
                    int mloc = R0 - by * 128;
                    #pragma unroll
                    for (int fn = 0; fn < 4; ++fn) {
                        int t = tcb + fn * 16;
                        f32x4 v = acc[fm][fn];
                        float4 rv = *(const float4*)(resF + (((size_t)(b * TN + t)) << 8) + R0);
                        int tloc = lr + fn * 16;
                        tile[(mloc + 0) * 68 + tloc] = v[0] + bias[R0 + 0] + rv.x;
                        tile[(mloc + 1) * 68 + tloc] = v[1] + bias[R0 + 1] + rv.y;
                        tile[(mloc + 2) * 68 + tloc] = v[2] + bias[R0 + 2] + rv.z;
                        tile[(mloc + 3) * 68 + tloc] = v[3] + bias[R0 + 3] + rv.w;
                    }
                }
            }
            __syncthreads();
            #pragma unroll
            for (int it = 0; it < 8; ++it) {
                int fid = it * 256 + tid;
                int m = fid >> 4, f = (fid & 15) << 2;
                float4 v = *(const float4*)&tile[m * 68 + f];
                *(float4*)(outF + ((size_t)(b * HN + by * 128 + m)) * TN + t0 + ht * 64 + f) = v;
            }
            __syncthreads();
        }
    } else {
        #pragma unroll
        for (int fm = 0; fm < 4; ++fm) {
            int R0 = mrow0 + fm * 16;
            #pragma unroll
            for (int fn = 0; fn < 4; ++fn) {
                int t = tcb + fn * 16;
                f32x4 v = acc[fm][fn];
                size_t rowoff = ((size_t)(b * TN + t)) << 8;
                if constexpr (GLU) {
                    int c_ = R0 >> 1;
                    float a0 = v[0] + bias[c_],     g0 = v[1] + bias[c_ + 256];
                    float a1 = v[2] + bias[c_ + 1], g1 = v[3] + bias[c_ + 257];
                    float o0 = a0 * sigm_f(g0), o1 = a1 * sigm_f(g1);
                    if constexpr (GELUOUT) { o0 = gelu_f(o0); o1 = gelu_f(o1); }
                    bf16x2 ov; ov[0] = (__bf16)o0; ov[1] = (__bf16)o1;
                    *(bf16x2*)(outB + rowoff + c_) = ov;
                } else {
                    float vv[4];
                    #pragma unroll
                    for (int j = 0; j < 4; ++j) vv[j] = v[j] + bias[R0 + j];
                    if constexpr (GELUOUT) {
                        #pragma unroll
                        for (int j = 0; j < 4; ++j) vv[j] = gelu_f(vv[j]);
                    }
                    bf16x4 ov;
                    #pragma unroll
                    for (int j = 0; j < 4; ++j) ov[j] = (__bf16)vv[j];
                    *(bf16x4*)(outB + rowoff + R0) = ov;
                }
            }
        }
    }
}

extern "C" void kernel_launch(void* const* d_in, const int* in_sizes, int n_in,
                              void* d_out, int out_size, void* d_ws, size_t ws_size,
                              hipStream_t stream)
{
    (void)in_sizes; (void)n_in; (void)out_size; (void)ws_size;
    const float* x      = (const float*)d_in[0];
    const float* log_dt = (const float*)d_in[1];
    const float* C_re   = (const float*)d_in[2];
    const float* C_im   = (const float*)d_in[3];
    const float* logAr  = (const float*)d_in[4];
    const float* A_im   = (const float*)d_in[5];
    const float* Dp     = (const float*)d_in[6];
    const float* outW   = (const float*)d_in[7];
    const float* outB   = (const float*)d_in[8];
    const float* ln1g   = (const float*)d_in[9];
    const float* ln1b   = (const float*)d_in[10];
    const float* lin1W  = (const float*)d_in[11];
    const float* lin1b  = (const float*)d_in[12];
    const float* gluW   = (const float*)d_in[13];
    const float* glub   = (const float*)d_in[14];
    const float* ln2g   = (const float*)d_in[15];
    const float* ln2b   = (const float*)d_in[16];
    const float* ff2aW  = (const float*)d_in[17];
    const float* ff2ab  = (const float*)d_in[18];
    const float* ff2bW  = (const float*)d_in[19];
    const float* ff2bb  = (const float*)d_in[20];
    float* out = (float*)d_out;

    char* ws = (char*)d_ws;
    const size_t MB = 1u << 20;
    float*  P    = (float*)(ws);
    float*  mu1  = (float*)(ws + 0x40000);
    float*  rs1  = (float*)(ws + 0x80000);
    float*  mu2  = (float*)(ws + 0xC0000);
    float*  rs2  = (float*)(ws + 0x100000);
    __bf16* WpO  = (__bf16*)(ws + 0x140000);
    __bf16* WpL  = (__bf16*)(ws + 0x180000);
    __bf16* WpG  = (__bf16*)(ws + 0x1A0000);
    __bf16* WpA  = (__bf16*)(ws + 0x220000);
    __bf16* WpB  = (__bf16*)(ws + 0x240000);
    __bf16* x_cl = (__bf16*)(ws + 4 * MB);     // 32MB [B][T][H] bf16
    char*   slB  = ws + 36 * MB;               // 32MB
    char*   slC  = ws + 68 * MB;               // 32MB
    float*  A_cl = (float*)(ws + 68 * MB);     // 64MB fp32

    prep_kernel<<<64, 64, 0, stream>>>(log_dt, C_re, C_im, logAr, A_im, P);
    prep_w_kernel<<<64, 256, 0, stream>>>(outW,  WpO, 256, 1);
    prep_w_kernel<<<32, 256, 0, stream>>>(lin1W, WpL, 256, 0);
    prep_w_kernel<<<128, 256, 0, stream>>>(gluW, WpG, 512, 1);
    prep_w_kernel<<<32, 256, 0, stream>>>(ff2aW, WpA, 256, 0);
    prep_w_kernel<<<32, 256, 0, stream>>>(ff2bW, WpB, 256, 0);

    ln_stats_kernel<<<dim3(32, BN), 256, 0, stream>>>(x, mu1, rs1);
    transpose_kernel<float><<<dim3(128, 4, BN), 256, 0, stream>>>(x, x_cl);

    __bf16* gu_raw = (__bf16*)slC;
    __bf16* gu_cl  = (__bf16*)slB;
    scan_kernel<<<2048, 256, 0, stream>>>(x, mu1, rs1, ln1g, ln1b, Dp, P, gu_raw);
    transpose_kernel<__bf16><<<dim3(128, 4, BN), 256, 0, stream>>>(gu_raw, gu_cl);

    dim3 g2(64, 2, BN), g4(64, 4, BN);
    __bf16* y2g = (__bf16*)slC;
    __bf16* y3  = (__bf16*)slB;
    __bf16* t1  = (__bf16*)slB;

    // GEMM1: y2g = gelu(GLU(outW · gu + outB))
    gemm_cl_kernel<256, true, false, false, true, 0><<<g4, 256, 0, stream>>>(
        gu_cl, nullptr, nullptr, WpO, outB, nullptr, nullptr, nullptr, nullptr,
        nullptr, nullptr, nullptr, y2g);
    // GEMM2: y3 = lin1 · y2g + lin1b
    gemm_cl_kernel<256, false, false, false, false, 0><<<g2, 256, 0, stream>>>(
        y2g, nullptr, nullptr, WpL, lin1b, nullptr, nullptr, nullptr, nullptr,
        nullptr, nullptr, nullptr, y3);
    // GEMM3: A_cl = x + GLU(gluW · [x_cl; y3] + glub)
    gemm_cl_kernel<512, true, true, false, false, 1><<<g4, 256, 0, stream>>>(
        x_cl, y3, nullptr, WpG, glub, nullptr, nullptr, nullptr, nullptr,
        nullptr, x_cl, A_cl, nullptr);
    ln_stats_cl_kernel<<<16384, 256, 0, stream>>>(A_cl, mu2, rs2);
    // GEMM4: t1 = gelu(ff2a · LN2(A) + ff2ab)
    gemm_cl_kernel<256, false, false, true, true, 0><<<g2, 256, 0, stream>>>(
        nullptr, nullptr, A_cl, WpA, ff2ab, mu2, rs2, ln2g, ln2b,
        nullptr, nullptr, nullptr, t1);
    // GEMM5: out = A + ff2b · t1 + ff2bb   (fp32 [B][H][T])
    gemm_cl_kernel<256, false, false, false, false, 2><<<g2, 256, 0, stream>>>(
        t1, nullptr, nullptr, WpB, ff2bb, nullptr, nullptr, nullptr, nullptr,
        A_cl, nullptr, out, nullptr);
}